// Round 14
// baseline (124.388 us; speedup 1.0000x reference)
//
#include <hip/hip_runtime.h>

typedef _Float16 f16;
typedef _Float16 f16x2 __attribute__((ext_vector_type(2)));
typedef _Float16 f16x8 __attribute__((ext_vector_type(8)));
typedef _Float16 f16x4 __attribute__((ext_vector_type(4)));
typedef float f32x4 __attribute__((ext_vector_type(4)));

#define GAS(p) ((const __attribute__((address_space(1))) void*)(p))
#define LAS(p) ((__attribute__((address_space(3))) void*)(p))

__device__ __forceinline__ f32x4 mfma16(f16x8 a, f16x8 b, f32x4 c) {
  return __builtin_amdgcn_mfma_f32_16x16x32_f16(a, b, c, 0, 0, 0);
}

__device__ __forceinline__ f16x2 cvt2(float a, float b) {
  return __builtin_bit_cast(f16x2, __builtin_amdgcn_cvt_pkrtz(a, b));
}

// Stage one 16B chunk per thread into a swizzled LDS tile (8 slots/row,
// 128B rows). LDS slot u of row r holds logical col-slot u^(r&7); linear
// LDS dest + inverse-swizzled global source.
__device__ __forceinline__ void stage_tile(const f16* __restrict__ grow0,
                                           int stride_f16, f16* lds, int t) {
  int r = t >> 3;
  int sw = ((t & 7) ^ (r & 7)) * 8;
  __builtin_amdgcn_global_load_lds(GAS(grow0 + r * stride_f16 + sw),
                                   LAS(lds + t * 8), 16, 0, 0);
}

// ---------------- fused fp32->fp16 converts + RoPE tables ----------------
__global__ void convall(const float* __restrict__ x, const float* __restrict__ wq,
                        const float* __restrict__ wk, const float* __restrict__ wv,
                        f16* __restrict__ xh, f16* __restrict__ wh,
                        float* __restrict__ cosT, float* __restrict__ sinT) {
  int bid = blockIdx.x;
  if (bid >= 3584) {  // RoPE tables [2048][32]
    int idx = (bid - 3584) * 256 + threadIdx.x;
    int n = idx >> 5, jj = idx & 31;
    float inv = powf(10000.0f, -(float)jj * (1.0f / 32.0f));
    float ang = (float)n * inv;
    cosT[idx] = cosf(ang);
    sinT[idx] = sinf(ang);
    return;
  }
  const float* s;
  f16* d;
  int boff;
  if (bid < 2048)      { s = x;  d = xh;            boff = bid; }
  else if (bid < 2560) { s = wq; d = wh;            boff = bid - 2048; }
  else if (bid < 3072) { s = wk; d = wh + 1048576;  boff = bid - 2560; }
  else                 { s = wv; d = wh + 2097152;  boff = bid - 3072; }
  int i = (boff * 256 + threadIdx.x) * 8;
  float4 a = *(const float4*)(s + i);
  float4 b = *(const float4*)(s + i + 4);
  f16x8 o = {(f16)a.x, (f16)a.y, (f16)a.z, (f16)a.w,
             (f16)b.x, (f16)b.y, (f16)b.z, (f16)b.w};
  *(f16x8*)(d + i) = o;
}

// ---------------- fused QKV GEMM + RoPE epilogue ----------------
// X: [4096][1024] f16, W: [3072][1024] f16 (Wq|Wk|Wv stacked)
// Q,K out: [32][2048][64] (RoPE applied, Q pre-scaled by log2e/8)
// Vt out:  [32][64][2048] with PERMUTED key coord (bits: p2=n4,p3=n2,p4=n3)
// so attn's PV A-fragment is one contiguous b128 / direct f16x8.
__global__ __launch_bounds__(256, 3) void qkv_gemm(
    const f16* __restrict__ X, const f16* __restrict__ W,
    const float* __restrict__ cosT, const float* __restrict__ sinT,
    f16* __restrict__ Q, f16* __restrict__ K, f16* __restrict__ Vt) {
  __shared__ f16 As[128 * 64];
  __shared__ f16 Bs[128 * 64];
  const int tid = threadIdx.x;
  const int wv = tid >> 6, lane = tid & 63;
  const int m0 = blockIdx.x * 128, n0 = blockIdx.y * 128;
  const int cl = lane & 15, g = lane >> 4;
  const int wr = (wv >> 1) * 64, wc = (wv & 1) * 64;
  const int vx = cl & 7;

  f32x4 acc[4][4] = {};
  const f16* ga = X + (size_t)m0 * 1024;
  const f16* gb = W + (size_t)n0 * 1024;

  for (int kt = 0; kt < 1024; kt += 64) {
    __syncthreads();
#pragma unroll
    for (int rd = 0; rd < 4; ++rd) {
      stage_tile(ga + kt, 1024, As, tid + rd * 256);
      stage_tile(gb + kt, 1024, Bs, tid + rd * 256);
    }
    __syncthreads();  // compiler drains vmcnt before barrier
#pragma unroll
    for (int kk = 0; kk < 2; ++kk) {
      f16x8 a[4], bf[4];
#pragma unroll
      for (int mi = 0; mi < 4; ++mi)
        a[mi] = *(const f16x8*)(As + (wr + mi * 16 + cl) * 64 +
                                (((kk * 4 + g) ^ vx) << 3));
#pragma unroll
      for (int ni = 0; ni < 4; ++ni)
        bf[ni] = *(const f16x8*)(Bs + (wc + ni * 16 + cl) * 64 +
                                 (((kk * 4 + g) ^ vx) << 3));
#pragma unroll
      for (int mi = 0; mi < 4; ++mi)
#pragma unroll
        for (int ni = 0; ni < 4; ++ni)
          acc[mi][ni] = mfma16(a[mi], bf[ni], acc[mi][ni]);
    }
  }

  // epilogue: C/D layout col=lane&15 row=(lane>>4)*4+reg
  const int p = n0 >> 10;  // 0=q 1=k 2=v
  for (int mi = 0; mi < 4; ++mi) {
    int rbase = m0 + wr + mi * 16 + g * 4;
    for (int ni = 0; ni < 4; ++ni) {
      int gc = n0 + wc + ni * 16 + cl;
      int f = gc & 1023;
      int h = f >> 6, d = f & 63;
      if (p < 2) {
        int j = d >> 1;
        f16* dst = (p == 0) ? Q : K;
        // Q pre-scale folds softmax 1/8 and log2(e) (exp2-domain scores)
        float sc = (p == 0) ? 0.18033688011f : 1.0f;
        for (int r = 0; r < 4; ++r) {
          int row = rbase + r;
          int bb = row >> 11, n = row & 2047;
          float co = cosT[n * 32 + j], si = sinT[n * 32 + j];
          float v = acc[mi][ni][r];
          float pr = __shfl_xor(v, 1);
          float o = (d & 1) ? (v * co + pr * si) : (v * co - pr * si);
          dst[((bb * 16 + h) * 2048 + n) * 64 + d] = (f16)(o * sc);
        }
      } else {
        int bb = rbase >> 11, n = rbase & 2047;
        // permuted key coord (4-aligned block): bits p2=n4, p3=n2, p4=n3
        int np = (n & ~31) | (((n >> 2) & 3) << 3) | (((n >> 4) & 1) << 2);
        f16x4 pk = {(f16)acc[mi][ni][0], (f16)acc[mi][ni][1],
                    (f16)acc[mi][ni][2], (f16)acc[mi][ni][3]};
        *(f16x4*)(Vt + (size_t)((bb * 16 + h) * 64 + d) * 2048 + np) = pk;
      }
    }
  }
}

// ---------------- flash attention fwd v14: K-LDS + V-direct, KVBLK=256 ----
// grid 512 x 256 thr; block = 128 q (4 waves x 32 q), KVBLK=256 (four
// 64-key sub-tiles per staged buffer), double-buffered K-ONLY LDS (64 KB),
// 8 iterations. V is NOT staged (m169: L2-resident via XCD pinning) —
// read direct global->register in A-phase, consumed by PV in B-phase
// (~500 cyc cover). Loop-top vmcnt(0) waits only the K staging (all V
// loads of an iteration are consumed within it). Static-max softmax
// p=2^s; V key-permuted so direct f16x8 reads are fragment-exact (v10-
// validated addressing).
__global__ __launch_bounds__(256, 2) void attn(
    const f16* __restrict__ Q, const f16* __restrict__ K,
    const f16* __restrict__ Vt, float* __restrict__ out) {
  __shared__ f16 Ks[2][4][4096];   // [buf][sub][key64 x d], swizzled slots
  const int tid = threadIdx.x;
  const int w = tid >> 6, lane = tid & 63;
  const int cl = lane & 15, g = lane >> 4;
  const int id = blockIdx.x;
  const int xcd = id & 7, j = id >> 3;  // XCD-grouped: 4 bh per XCD
  const int bh = xcd * 4 + (j >> 4);
  const int b = bh >> 4, h = bh & 15;
  const int qb = (j & 15) * 128 + w * 32;  // wave's 32-q base
  const f16* Qp = Q + (size_t)bh * (2048 * 64);
  const f16* Kp = K + (size_t)bh * (2048 * 64);
  const f16* Vp = Vt + (size_t)bh * (64 * 2048);

  // Q as B-operand: col=q=cl (per half), k=d (pre-scaled by log2e/8)
  f16x8 bq[2][2];
#pragma unroll
  for (int qh = 0; qh < 2; ++qh) {
    bq[qh][0] = *(const f16x8*)(Qp + (qb + qh * 16 + cl) * 64 + g * 8);
    bq[qh][1] = *(const f16x8*)(Qp + (qb + qh * 16 + cl) * 64 + 32 + g * 8);
  }

  f32x4 acc[2][4] = {};   // acc[qh][dblk]: O^T[d=dblk*16+g*4+r][q]
  float lsp[2] = {0.f, 0.f};
  const int vx = cl & 7;
  const f32x4 z4 = {0.f, 0.f, 0.f, 0.f};
  union PB { f16x8 v; f16x2 hx[4]; };
  struct AS { f32x4 s[2][4]; f16x8 vf[2][4]; };
  const f16* vbase = Vp + (size_t)cl * 2048 + g * 8;  // + d*32768 + kt2 + ks*32

  // stage one 256-key K tile (four 64-key sub-tiles): 8 gload_lds per wave
  auto STAGE = [&](int it, int bf) {
    const f16* kp = Kp + (size_t)it * 16384;
#pragma unroll
    for (int sub = 0; sub < 4; ++sub) {
      stage_tile(kp + sub * 4096, 64, Ks[bf][sub], tid);
      stage_tile(kp + sub * 4096, 64, Ks[bf][sub], tid + 256);
    }
  };

  // A-phase: K frags (LDS) + QK^T; V frags DIRECT from global (v10 pattern)
  auto APH = [&](const f16* kb, int kt2, AS& S) {
    const f16* vp = vbase + kt2;
#pragma unroll
    for (int ks = 0; ks < 2; ++ks)
#pragma unroll
      for (int d = 0; d < 4; ++d)
        S.vf[ks][d] = *(const f16x8*)(vp + (size_t)d * 32768 + ks * 32);
    f16x8 a0[4], a1[4];
#pragma unroll
    for (int i = 0; i < 4; ++i) {
      const f16* kr = kb + (i * 16 + cl) * 64;
      a0[i] = *(const f16x8*)(kr + ((g ^ vx) << 3));
      a1[i] = *(const f16x8*)(kr + (((4 + g) ^ vx) << 3));
    }
    __builtin_amdgcn_s_setprio(1);
#pragma unroll
    for (int qh = 0; qh < 2; ++qh)
#pragma unroll
      for (int i = 0; i < 4; ++i)
        S.s[qh][i] = mfma16(a1[i], bq[qh][1], mfma16(a0[i], bq[qh][0], z4));
    __builtin_amdgcn_s_setprio(0);
  };

  // B-phase: softmax + PV, registers only
  auto BPH = [&](AS& S) {
    PB pb[2][2];
#pragma unroll
    for (int qh = 0; qh < 2; ++qh) {
      float p0 = exp2f(S.s[qh][0][0]), p1 = exp2f(S.s[qh][0][1]);
      float p2 = exp2f(S.s[qh][0][2]), p3 = exp2f(S.s[qh][0][3]);
      float p4 = exp2f(S.s[qh][1][0]), p5 = exp2f(S.s[qh][1][1]);
      float p6 = exp2f(S.s[qh][1][2]), p7 = exp2f(S.s[qh][1][3]);
      float p8 = exp2f(S.s[qh][2][0]), p9 = exp2f(S.s[qh][2][1]);
      float pa = exp2f(S.s[qh][2][2]), pc = exp2f(S.s[qh][2][3]);
      float pd = exp2f(S.s[qh][3][0]), pe = exp2f(S.s[qh][3][1]);
      float pf = exp2f(S.s[qh][3][2]), pg = exp2f(S.s[qh][3][3]);
      lsp[qh] += (((p0 + p1) + (p2 + p3)) + ((p4 + p5) + (p6 + p7))) +
                 (((p8 + p9) + (pa + pc)) + ((pd + pe) + (pf + pg)));
      pb[qh][0].hx[0] = cvt2(p0, p1); pb[qh][0].hx[1] = cvt2(p2, p3);
      pb[qh][0].hx[2] = cvt2(p4, p5); pb[qh][0].hx[3] = cvt2(p6, p7);
      pb[qh][1].hx[0] = cvt2(p8, p9); pb[qh][1].hx[1] = cvt2(pa, pc);
      pb[qh][1].hx[2] = cvt2(pd, pe); pb[qh][1].hx[3] = cvt2(pf, pg);
    }
    __builtin_amdgcn_s_setprio(1);
#pragma unroll
    for (int ks = 0; ks < 2; ++ks)
#pragma unroll
      for (int d = 0; d < 4; ++d) {
        acc[0][d] = mfma16(S.vf[ks][d], pb[0][ks].v, acc[0][d]);
        acc[1][d] = mfma16(S.vf[ks][d], pb[1][ks].v, acc[1][d]);
      }
    __builtin_amdgcn_s_setprio(0);
  };

  STAGE(0, 0);
  AS P, Q2;
  int cur = 0;
  for (int it = 0; it < 8; ++it) {
    const int kt = it * 256;
    asm volatile("s_waitcnt vmcnt(0)" ::: "memory");  // K tile `it` landed
    __builtin_amdgcn_s_barrier();                     // + prev readers done
    if (it + 1 < 8) STAGE(it + 1, cur ^ 1);
    // 4 sub-tiles, 2-deep A/B pipeline fully inside the iteration
    APH(Ks[cur][0], kt, P);
    APH(Ks[cur][1], kt + 64, Q2);
    BPH(P);
    APH(Ks[cur][2], kt + 128, P);
    BPH(Q2);
    APH(Ks[cur][3], kt + 192, Q2);
    BPH(P);
    BPH(Q2);
    cur ^= 1;
  }

#pragma unroll
  for (int qh = 0; qh < 2; ++qh) {
    float ls = lsp[qh];
    ls += __shfl_xor(ls, 16);
    ls += __shfl_xor(ls, 32);
    float inv = 1.0f / ls;
    float* ob = out + (size_t)(b * 2048 + qb + qh * 16 + cl) * 1024 +
                h * 64 + g * 4;
#pragma unroll
    for (int d = 0; d < 4; ++d) {
      float4 o = {acc[qh][d][0] * inv, acc[qh][d][1] * inv,
                  acc[qh][d][2] * inv, acc[qh][d][3] * inv};
      *(float4*)(ob + (size_t)d * 16) = o;
    }
  }
}

extern "C" void kernel_launch(void* const* d_in, const int* in_sizes, int n_in,
                              void* d_out, int out_size, void* d_ws, size_t ws_size,
                              hipStream_t stream) {
  const float* x  = (const float*)d_in[0];
  const float* Wq = (const float*)d_in[1];
  const float* Wk = (const float*)d_in[2];
  const float* Wv = (const float*)d_in[3];
  float* out = (float*)d_out;
  char* ws = (char*)d_ws;

  f16* xh   = (f16*)(ws);                       // 8388608 B
  f16* wh   = (f16*)(ws + 8388608);             // 6291456 B
  f16* Qr   = (f16*)(ws + 14680064);            // 8388608 B
  f16* Kr   = (f16*)(ws + 23068672);            // 8388608 B
  f16* Vt   = (f16*)(ws + 31457280);            // 8388608 B
  float* cosT = (float*)(ws + 39845888);        // 262144 B
  float* sinT = (float*)(ws + 40108032);        // total ~40.4 MB

  convall<<<3840, 256, 0, stream>>>(x, Wq, Wk, Wv, xh, wh, cosT, sinT);

  dim3 g1(32, 24);
  qkv_gemm<<<g1, 256, 0, stream>>>(xh, wh, cosT, sinT, Qr, Kr, Vt);

  attn<<<512, 256, 0, stream>>>(Qr, Kr, Vt, out);
}

// Round 15
// 81.823 us; speedup vs baseline: 1.5202x; 1.5202x over previous
//
#include <hip/hip_runtime.h>

typedef _Float16 f16;
typedef _Float16 f16x2 __attribute__((ext_vector_type(2)));
typedef _Float16 f16x8 __attribute__((ext_vector_type(8)));
typedef _Float16 f16x4 __attribute__((ext_vector_type(4)));
typedef float f32x4 __attribute__((ext_vector_type(4)));

#define GAS(p) ((const __attribute__((address_space(1))) void*)(p))
#define LAS(p) ((__attribute__((address_space(3))) void*)(p))

__device__ __forceinline__ f32x4 mfma16(f16x8 a, f16x8 b, f32x4 c) {
  return __builtin_amdgcn_mfma_f32_16x16x32_f16(a, b, c, 0, 0, 0);
}

__device__ __forceinline__ f16x2 cvt2(float a, float b) {
  return __builtin_bit_cast(f16x2, __builtin_amdgcn_cvt_pkrtz(a, b));
}

// Raw v_exp_f32 (2^x). Scores are bounded (|s| <~ 10), so libm exp2f's
// denormal-range fixup (~5 VALU ops/call) is pure waste at 134M calls.
__device__ __forceinline__ float fexp2(float x) {
#if __has_builtin(__builtin_amdgcn_exp2f)
  return __builtin_amdgcn_exp2f(x);
#else
  float r;
  asm("v_exp_f32 %0, %1" : "=v"(r) : "v"(x));
  return r;
#endif
}

// Stage one 16B chunk per thread into a swizzled LDS tile (8 slots/row,
// 128B rows). LDS slot u of row r holds logical col-slot u^(r&7); linear
// LDS dest + inverse-swizzled global source.
__device__ __forceinline__ void stage_tile(const f16* __restrict__ grow0,
                                           int stride_f16, f16* lds, int t) {
  int r = t >> 3;
  int sw = ((t & 7) ^ (r & 7)) * 8;
  __builtin_amdgcn_global_load_lds(GAS(grow0 + r * stride_f16 + sw),
                                   LAS(lds + t * 8), 16, 0, 0);
}

// ---------------- fused fp32->fp16 converts + RoPE tables ----------------
__global__ void convall(const float* __restrict__ x, const float* __restrict__ wq,
                        const float* __restrict__ wk, const float* __restrict__ wv,
                        f16* __restrict__ xh, f16* __restrict__ wh,
                        float* __restrict__ cosT, float* __restrict__ sinT) {
  int bid = blockIdx.x;
  if (bid >= 3584) {  // RoPE tables [2048][32]
    int idx = (bid - 3584) * 256 + threadIdx.x;
    int n = idx >> 5, jj = idx & 31;
    float inv = powf(10000.0f, -(float)jj * (1.0f / 32.0f));
    float ang = (float)n * inv;
    cosT[idx] = cosf(ang);
    sinT[idx] = sinf(ang);
    return;
  }
  const float* s;
  f16* d;
  int boff;
  if (bid < 2048)      { s = x;  d = xh;            boff = bid; }
  else if (bid < 2560) { s = wq; d = wh;            boff = bid - 2048; }
  else if (bid < 3072) { s = wk; d = wh + 1048576;  boff = bid - 2560; }
  else                 { s = wv; d = wh + 2097152;  boff = bid - 3072; }
  int i = (boff * 256 + threadIdx.x) * 8;
  float4 a = *(const float4*)(s + i);
  float4 b = *(const float4*)(s + i + 4);
  f16x8 o = {(f16)a.x, (f16)a.y, (f16)a.z, (f16)a.w,
             (f16)b.x, (f16)b.y, (f16)b.z, (f16)b.w};
  *(f16x8*)(d + i) = o;
}

// ---------------- fused QKV GEMM + RoPE epilogue ----------------
// X: [4096][1024] f16, W: [3072][1024] f16 (Wq|Wk|Wv stacked)
// Q,K out: [32][2048][64] (RoPE applied, Q pre-scaled by log2e/8)
// Vt out:  [32][64][2048] with PERMUTED key coord (bits: p2=n4,p3=n2,p4=n3)
// so attn's PV A-fragment is one contiguous b128.
__global__ __launch_bounds__(256, 3) void qkv_gemm(
    const f16* __restrict__ X, const f16* __restrict__ W,
    const float* __restrict__ cosT, const float* __restrict__ sinT,
    f16* __restrict__ Q, f16* __restrict__ K, f16* __restrict__ Vt) {
  __shared__ f16 As[128 * 64];
  __shared__ f16 Bs[128 * 64];
  const int tid = threadIdx.x;
  const int wv = tid >> 6, lane = tid & 63;
  const int m0 = blockIdx.x * 128, n0 = blockIdx.y * 128;
  const int cl = lane & 15, g = lane >> 4;
  const int wr = (wv >> 1) * 64, wc = (wv & 1) * 64;
  const int vx = cl & 7;

  f32x4 acc[4][4] = {};
  const f16* ga = X + (size_t)m0 * 1024;
  const f16* gb = W + (size_t)n0 * 1024;

  for (int kt = 0; kt < 1024; kt += 64) {
    __syncthreads();
#pragma unroll
    for (int rd = 0; rd < 4; ++rd) {
      stage_tile(ga + kt, 1024, As, tid + rd * 256);
      stage_tile(gb + kt, 1024, Bs, tid + rd * 256);
    }
    __syncthreads();  // compiler drains vmcnt before barrier
#pragma unroll
    for (int kk = 0; kk < 2; ++kk) {
      f16x8 a[4], bf[4];
#pragma unroll
      for (int mi = 0; mi < 4; ++mi)
        a[mi] = *(const f16x8*)(As + (wr + mi * 16 + cl) * 64 +
                                (((kk * 4 + g) ^ vx) << 3));
#pragma unroll
      for (int ni = 0; ni < 4; ++ni)
        bf[ni] = *(const f16x8*)(Bs + (wc + ni * 16 + cl) * 64 +
                                 (((kk * 4 + g) ^ vx) << 3));
#pragma unroll
      for (int mi = 0; mi < 4; ++mi)
#pragma unroll
        for (int ni = 0; ni < 4; ++ni)
          acc[mi][ni] = mfma16(a[mi], bf[ni], acc[mi][ni]);
    }
  }

  // epilogue: C/D layout col=lane&15 row=(lane>>4)*4+reg
  const int p = n0 >> 10;  // 0=q 1=k 2=v
  for (int mi = 0; mi < 4; ++mi) {
    int rbase = m0 + wr + mi * 16 + g * 4;
    for (int ni = 0; ni < 4; ++ni) {
      int gc = n0 + wc + ni * 16 + cl;
      int f = gc & 1023;
      int h = f >> 6, d = f & 63;
      if (p < 2) {
        int j = d >> 1;
        f16* dst = (p == 0) ? Q : K;
        // Q pre-scale folds softmax 1/8 and log2(e) (exp2-domain scores)
        float sc = (p == 0) ? 0.18033688011f : 1.0f;
        for (int r = 0; r < 4; ++r) {
          int row = rbase + r;
          int bb = row >> 11, n = row & 2047;
          float co = cosT[n * 32 + j], si = sinT[n * 32 + j];
          float v = acc[mi][ni][r];
          float pr = __shfl_xor(v, 1);
          float o = (d & 1) ? (v * co + pr * si) : (v * co - pr * si);
          dst[((bb * 16 + h) * 2048 + n) * 64 + d] = (f16)(o * sc);
        }
      } else {
        int bb = rbase >> 11, n = rbase & 2047;
        // permuted key coord (4-aligned block): bits p2=n4, p3=n2, p4=n3
        int np = (n & ~31) | (((n >> 2) & 3) << 3) | (((n >> 4) & 1) << 2);
        f16x4 pk = {(f16)acc[mi][ni][0], (f16)acc[mi][ni][1],
                    (f16)acc[mi][ni][2], (f16)acc[mi][ni][3]};
        *(f16x4*)(Vt + (size_t)((bb * 16 + h) * 64 + d) * 2048 + np) = pk;
      }
    }
  }
}

// ---------------- flash attention fwd v15: v13 + VALU-issue cuts ----------
// Structure identical to v13 (best measured: 63.9 us): KVBLK=128, two
// 64-key sub-tiles/buffer, double-buffered, 2-deep A/B pipeline,
// V-frags to registers in A-phase. Changes:
//  (1) raw v_exp_f32 via builtin (drops libm denormal fixup ~5 VALU/call),
//  (2) softmax denominator via ones-MFMA: acc1 += mfma(1, pb) sums P over
//      the full k=32 inside the matrix pipe — removes 32 adds/subtile AND
//      the final cross-lane shfl reduce (MFMA already sums across groups).
__global__ __launch_bounds__(256, 2) void attn(
    const f16* __restrict__ Q, const f16* __restrict__ K,
    const f16* __restrict__ Vt, float* __restrict__ out) {
  __shared__ f16 Ks[2][2][4096];   // [buf][half][key64 x d], swizzled slots
  __shared__ f16 Vs[2][2][4096];   // [buf][half][d x key64'], swizzled slots
  const int tid = threadIdx.x;
  const int w = tid >> 6, lane = tid & 63;
  const int cl = lane & 15, g = lane >> 4;
  const int id = blockIdx.x;
  const int xcd = id & 7, j = id >> 3;  // XCD-grouped: 4 bh per XCD
  const int bh = xcd * 4 + (j >> 4);
  const int b = bh >> 4, h = bh & 15;
  const int qb = (j & 15) * 128 + w * 32;  // wave's 32-q base
  const f16* Qp = Q + (size_t)bh * (2048 * 64);
  const f16* Kp = K + (size_t)bh * (2048 * 64);
  const f16* Vp = Vt + (size_t)bh * (64 * 2048);

  // Q as B-operand: col=q=cl (per half), k=d (pre-scaled by log2e/8)
  f16x8 bq[2][2];
#pragma unroll
  for (int qh = 0; qh < 2; ++qh) {
    bq[qh][0] = *(const f16x8*)(Qp + (qb + qh * 16 + cl) * 64 + g * 8);
    bq[qh][1] = *(const f16x8*)(Qp + (qb + qh * 16 + cl) * 64 + 32 + g * 8);
  }

  f32x4 acc[2][4] = {};   // acc[qh][dblk]: O^T[d=dblk*16+g*4+r][q]
  f32x4 acc1[2] = {};     // ones-MFMA denominator: acc1[qh][r] = sum_k P
  const f16x8 kones = {(f16)1, (f16)1, (f16)1, (f16)1,
                       (f16)1, (f16)1, (f16)1, (f16)1};
  const int vx = cl & 7;
  const f32x4 z4 = {0.f, 0.f, 0.f, 0.f};
  union PB { f16x8 v; f16x2 hx[4]; };
  struct AS { f32x4 s[2][4]; f16x8 vf[2][4]; };  // 64 VGPR per set

  // stage one 128-key tile (two 64-key halves): 8 gload_lds per wave
  auto STAGE = [&](int it, int bf) {
    const f16* kp = Kp + (size_t)it * 8192;
    const f16* vp = Vp + (size_t)it * 128;
#pragma unroll
    for (int hh = 0; hh < 2; ++hh) {
      stage_tile(kp + hh * 4096, 64, Ks[bf][hh], tid);
      stage_tile(kp + hh * 4096, 64, Ks[bf][hh], tid + 256);
      stage_tile(vp + hh * 64, 2048, Vs[bf][hh], tid);
      stage_tile(vp + hh * 64, 2048, Vs[bf][hh], tid + 256);
    }
  };

  // A-phase: K-frag reads + QK^T; V-frags pre-loaded to registers
  auto APH = [&](const f16* kb, const f16* vb, AS& S) {
    f16x8 a0[4], a1[4];
#pragma unroll
    for (int i = 0; i < 4; ++i) {
      const f16* kr = kb + (i * 16 + cl) * 64;
      a0[i] = *(const f16x8*)(kr + ((g ^ vx) << 3));
      a1[i] = *(const f16x8*)(kr + (((4 + g) ^ vx) << 3));
    }
#pragma unroll
    for (int ks = 0; ks < 2; ++ks)
#pragma unroll
      for (int d = 0; d < 4; ++d)
        S.vf[ks][d] = *(const f16x8*)(vb + (d * 16 + cl) * 64 +
                                      (((ks * 4 + g) ^ vx) << 3));
    __builtin_amdgcn_s_setprio(1);
#pragma unroll
    for (int qh = 0; qh < 2; ++qh)
#pragma unroll
      for (int i = 0; i < 4; ++i)
        S.s[qh][i] = mfma16(a1[i], bq[qh][1], mfma16(a0[i], bq[qh][0], z4));
    __builtin_amdgcn_s_setprio(0);
  };

  // B-phase: softmax (raw v_exp) + PV + ones-MFMA denominator
  auto BPH = [&](AS& S) {
    PB pb[2][2];
#pragma unroll
    for (int qh = 0; qh < 2; ++qh) {
      float p0 = fexp2(S.s[qh][0][0]), p1 = fexp2(S.s[qh][0][1]);
      float p2 = fexp2(S.s[qh][0][2]), p3 = fexp2(S.s[qh][0][3]);
      float p4 = fexp2(S.s[qh][1][0]), p5 = fexp2(S.s[qh][1][1]);
      float p6 = fexp2(S.s[qh][1][2]), p7 = fexp2(S.s[qh][1][3]);
      float p8 = fexp2(S.s[qh][2][0]), p9 = fexp2(S.s[qh][2][1]);
      float pa = fexp2(S.s[qh][2][2]), pc = fexp2(S.s[qh][2][3]);
      float pd = fexp2(S.s[qh][3][0]), pe = fexp2(S.s[qh][3][1]);
      float pf = fexp2(S.s[qh][3][2]), pg = fexp2(S.s[qh][3][3]);
      pb[qh][0].hx[0] = cvt2(p0, p1); pb[qh][0].hx[1] = cvt2(p2, p3);
      pb[qh][0].hx[2] = cvt2(p4, p5); pb[qh][0].hx[3] = cvt2(p6, p7);
      pb[qh][1].hx[0] = cvt2(p8, p9); pb[qh][1].hx[1] = cvt2(pa, pc);
      pb[qh][1].hx[2] = cvt2(pd, pe); pb[qh][1].hx[3] = cvt2(pf, pg);
    }
    __builtin_amdgcn_s_setprio(1);
#pragma unroll
    for (int ks = 0; ks < 2; ++ks) {
#pragma unroll
      for (int d = 0; d < 4; ++d) {
        acc[0][d] = mfma16(S.vf[ks][d], pb[0][ks].v, acc[0][d]);
        acc[1][d] = mfma16(S.vf[ks][d], pb[1][ks].v, acc[1][d]);
      }
      acc1[0] = mfma16(kones, pb[0][ks].v, acc1[0]);
      acc1[1] = mfma16(kones, pb[1][ks].v, acc1[1]);
    }
    __builtin_amdgcn_s_setprio(0);
  };

  // prologue
  STAGE(0, 0);
  asm volatile("s_waitcnt vmcnt(0)" ::: "memory");
  __builtin_amdgcn_s_barrier();
  STAGE(1, 1);
  AS P, Qs;
  APH(Ks[0][0], Vs[0][0], P);   // sub-tile 0

  for (int it = 0; it < 16; ++it) {
    const int c = it & 1;
    // sub-tile 2it+1 (same buffer) while finishing 2it
    APH(Ks[c][1], Vs[c][1], Qs);
    BPH(P);
    if (it < 15) {
      asm volatile("s_waitcnt vmcnt(0)" ::: "memory");  // tile it+1 landed
      __builtin_amdgcn_s_barrier();                      // buf c readers done
      if (it + 2 < 16) STAGE(it + 2, c);
      // sub-tile 2it+2 (next buffer) while finishing 2it+1
      APH(Ks[c ^ 1][0], Vs[c ^ 1][0], P);
      BPH(Qs);
    } else {
      BPH(Qs);
    }
  }

  // acc1[qh] already holds the FULL denominator per col q (MFMA summed
  // across all k-groups) — no cross-lane reduce needed.
#pragma unroll
  for (int qh = 0; qh < 2; ++qh) {
    float inv = 1.0f / acc1[qh][0];
    float* ob = out + (size_t)(b * 2048 + qb + qh * 16 + cl) * 1024 +
                h * 64 + g * 4;
#pragma unroll
    for (int d = 0; d < 4; ++d) {
      float4 o = {acc[qh][d][0] * inv, acc[qh][d][1] * inv,
                  acc[qh][d][2] * inv, acc[qh][d][3] * inv};
      *(float4*)(ob + (size_t)d * 16) = o;
    }
  }
}

extern "C" void kernel_launch(void* const* d_in, const int* in_sizes, int n_in,
                              void* d_out, int out_size, void* d_ws, size_t ws_size,
                              hipStream_t stream) {
  const float* x  = (const float*)d_in[0];
  const float* Wq = (const float*)d_in[1];
  const float* Wk = (const float*)d_in[2];
  const float* Wv = (const float*)d_in[3];
  float* out = (float*)d_out;
  char* ws = (char*)d_ws;

  f16* xh   = (f16*)(ws);                       // 8388608 B
  f16* wh   = (f16*)(ws + 8388608);             // 6291456 B
  f16* Qr   = (f16*)(ws + 14680064);            // 8388608 B
  f16* Kr   = (f16*)(ws + 23068672);            // 8388608 B
  f16* Vt   = (f16*)(ws + 31457280);            // 8388608 B
  float* cosT = (float*)(ws + 39845888);        // 262144 B
  float* sinT = (float*)(ws + 40108032);        // total ~40.4 MB

  convall<<<3840, 256, 0, stream>>>(x, Wq, Wk, Wv, xh, wh, cosT, sinT);

  dim3 g1(32, 24);
  qkv_gemm<<<g1, 256, 0, stream>>>(xh, wh, cosT, sinT, Qr, Kr, Vt);

  attn<<<512, 256, 0, stream>>>(Qr, Kr, Vt, out);
}

// Round 16
// 81.447 us; speedup vs baseline: 1.5272x; 1.0046x over previous
//
#include <hip/hip_runtime.h>

typedef _Float16 f16;
typedef _Float16 f16x2 __attribute__((ext_vector_type(2)));
typedef _Float16 f16x8 __attribute__((ext_vector_type(8)));
typedef _Float16 f16x4 __attribute__((ext_vector_type(4)));
typedef float f32x4 __attribute__((ext_vector_type(4)));

#define GAS(p) ((const __attribute__((address_space(1))) void*)(p))
#define LAS(p) ((__attribute__((address_space(3))) void*)(p))

__device__ __forceinline__ f32x4 mfma16(f16x8 a, f16x8 b, f32x4 c) {
  return __builtin_amdgcn_mfma_f32_16x16x32_f16(a, b, c, 0, 0, 0);
}

__device__ __forceinline__ f16x2 cvt2(float a, float b) {
  return __builtin_bit_cast(f16x2, __builtin_amdgcn_cvt_pkrtz(a, b));
}

// Raw v_exp_f32 (2^x). Scores are bounded (|s| <~ 10), so libm exp2f's
// denormal-range fixup (~5 VALU ops/call) is pure waste at 134M calls.
__device__ __forceinline__ float fexp2(float x) {
#if __has_builtin(__builtin_amdgcn_exp2f)
  return __builtin_amdgcn_exp2f(x);
#else
  float r;
  asm("v_exp_f32 %0, %1" : "=v"(r) : "v"(x));
  return r;
#endif
}

// Stage one 16B chunk per thread into a swizzled LDS tile (8 slots/row,
// 128B rows). LDS slot u of row r holds logical col-slot u^(r&7); linear
// LDS dest + inverse-swizzled global source.
__device__ __forceinline__ void stage_tile(const f16* __restrict__ grow0,
                                           int stride_f16, f16* lds, int t) {
  int r = t >> 3;
  int sw = ((t & 7) ^ (r & 7)) * 8;
  __builtin_amdgcn_global_load_lds(GAS(grow0 + r * stride_f16 + sw),
                                   LAS(lds + t * 8), 16, 0, 0);
}

// ---------------- fused fp32->fp16 converts + RoPE tables ----------------
__global__ void convall(const float* __restrict__ x, const float* __restrict__ wq,
                        const float* __restrict__ wk, const float* __restrict__ wv,
                        f16* __restrict__ xh, f16* __restrict__ wh,
                        float* __restrict__ cosT, float* __restrict__ sinT) {
  int bid = blockIdx.x;
  if (bid >= 3584) {  // RoPE tables [2048][32]
    int idx = (bid - 3584) * 256 + threadIdx.x;
    int n = idx >> 5, jj = idx & 31;
    float inv = powf(10000.0f, -(float)jj * (1.0f / 32.0f));
    float ang = (float)n * inv;
    cosT[idx] = cosf(ang);
    sinT[idx] = sinf(ang);
    return;
  }
  const float* s;
  f16* d;
  int boff;
  if (bid < 2048)      { s = x;  d = xh;            boff = bid; }
  else if (bid < 2560) { s = wq; d = wh;            boff = bid - 2048; }
  else if (bid < 3072) { s = wk; d = wh + 1048576;  boff = bid - 2560; }
  else                 { s = wv; d = wh + 2097152;  boff = bid - 3072; }
  int i = (boff * 256 + threadIdx.x) * 8;
  float4 a = *(const float4*)(s + i);
  float4 b = *(const float4*)(s + i + 4);
  f16x8 o = {(f16)a.x, (f16)a.y, (f16)a.z, (f16)a.w,
             (f16)b.x, (f16)b.y, (f16)b.z, (f16)b.w};
  *(f16x8*)(d + i) = o;
}

// ---------------- fused QKV GEMM + RoPE epilogue ----------------
// X: [4096][1024] f16, W: [3072][1024] f16 (Wq|Wk|Wv stacked)
// Q,K out: [32][2048][64] (RoPE applied, Q pre-scaled by log2e/8)
// Vt out:  [32][64][2048] with PERMUTED key coord (bits: p2=n4,p3=n2,p4=n3)
// so attn's PV A-fragment is one contiguous b128.
// 1D grid 768, XCD-swizzled: each XCD owns a 4-mrow x 24-ncol stripe,
// m-inner order -> A-panels (1 MB) L2-resident, B-panel reused 4x hot.
__global__ __launch_bounds__(256, 3) void qkv_gemm(
    const f16* __restrict__ X, const f16* __restrict__ W,
    const float* __restrict__ cosT, const float* __restrict__ sinT,
    f16* __restrict__ Q, f16* __restrict__ K, f16* __restrict__ Vt) {
  __shared__ f16 As[128 * 64];
  __shared__ f16 Bs[128 * 64];
  const int tid = threadIdx.x;
  const int wv = tid >> 6, lane = tid & 63;
  const int lin = blockIdx.x;            // 0..767 (768 % 8 == 0: bijective)
  const int xcd = lin & 7, idx = lin >> 3;   // idx 0..95 per XCD
  const int m0 = (xcd * 4 + (idx & 3)) * 128;  // 4 m-rows per XCD
  const int n0 = (idx >> 2) * 128;             // 24 n-cols, m-inner order
  const int cl = lane & 15, g = lane >> 4;
  const int wr = (wv >> 1) * 64, wc = (wv & 1) * 64;
  const int vx = cl & 7;

  f32x4 acc[4][4] = {};
  const f16* ga = X + (size_t)m0 * 1024;
  const f16* gb = W + (size_t)n0 * 1024;

  for (int kt = 0; kt < 1024; kt += 64) {
    __syncthreads();
#pragma unroll
    for (int rd = 0; rd < 4; ++rd) {
      stage_tile(ga + kt, 1024, As, tid + rd * 256);
      stage_tile(gb + kt, 1024, Bs, tid + rd * 256);
    }
    __syncthreads();  // compiler drains vmcnt before barrier
#pragma unroll
    for (int kk = 0; kk < 2; ++kk) {
      f16x8 a[4], bf[4];
#pragma unroll
      for (int mi = 0; mi < 4; ++mi)
        a[mi] = *(const f16x8*)(As + (wr + mi * 16 + cl) * 64 +
                                (((kk * 4 + g) ^ vx) << 3));
#pragma unroll
      for (int ni = 0; ni < 4; ++ni)
        bf[ni] = *(const f16x8*)(Bs + (wc + ni * 16 + cl) * 64 +
                                 (((kk * 4 + g) ^ vx) << 3));
#pragma unroll
      for (int mi = 0; mi < 4; ++mi)
#pragma unroll
        for (int ni = 0; ni < 4; ++ni)
          acc[mi][ni] = mfma16(a[mi], bf[ni], acc[mi][ni]);
    }
  }

  // epilogue: C/D layout col=lane&15 row=(lane>>4)*4+reg
  const int p = n0 >> 10;  // 0=q 1=k 2=v
  for (int mi = 0; mi < 4; ++mi) {
    int rbase = m0 + wr + mi * 16 + g * 4;
    for (int ni = 0; ni < 4; ++ni) {
      int gc = n0 + wc + ni * 16 + cl;
      int f = gc & 1023;
      int h = f >> 6, d = f & 63;
      if (p < 2) {
        int j = d >> 1;
        f16* dst = (p == 0) ? Q : K;
        // Q pre-scale folds softmax 1/8 and log2(e) (exp2-domain scores)
        float sc = (p == 0) ? 0.18033688011f : 1.0f;
        for (int r = 0; r < 4; ++r) {
          int row = rbase + r;
          int bb = row >> 11, n = row & 2047;
          float co = cosT[n * 32 + j], si = sinT[n * 32 + j];
          float v = acc[mi][ni][r];
          float pr = __shfl_xor(v, 1);
          float o = (d & 1) ? (v * co + pr * si) : (v * co - pr * si);
          dst[((bb * 16 + h) * 2048 + n) * 64 + d] = (f16)(o * sc);
        }
      } else {
        int bb = rbase >> 11, n = rbase & 2047;
        // permuted key coord (4-aligned block): bits p2=n4, p3=n2, p4=n3
        int np = (n & ~31) | (((n >> 2) & 3) << 3) | (((n >> 4) & 1) << 2);
        f16x4 pk = {(f16)acc[mi][ni][0], (f16)acc[mi][ni][1],
                    (f16)acc[mi][ni][2], (f16)acc[mi][ni][3]};
        *(f16x4*)(Vt + (size_t)((bb * 16 + h) * 64 + d) * 2048 + np) = pk;
      }
    }
  }
}

// ---------------- flash attention fwd v15 (unchanged: 45.0 us) ------------
// KVBLK=128, two 64-key sub-tiles/buffer, double-buffered, 2-deep A/B
// pipeline, V-frags to registers in A-phase, raw v_exp_f32 softmax,
// ones-MFMA denominator (no cross-lane reduce).
__global__ __launch_bounds__(256, 2) void attn(
    const f16* __restrict__ Q, const f16* __restrict__ K,
    const f16* __restrict__ Vt, float* __restrict__ out) {
  __shared__ f16 Ks[2][2][4096];   // [buf][half][key64 x d], swizzled slots
  __shared__ f16 Vs[2][2][4096];   // [buf][half][d x key64'], swizzled slots
  const int tid = threadIdx.x;
  const int w = tid >> 6, lane = tid & 63;
  const int cl = lane & 15, g = lane >> 4;
  const int id = blockIdx.x;
  const int xcd = id & 7, j = id >> 3;  // XCD-grouped: 4 bh per XCD
  const int bh = xcd * 4 + (j >> 4);
  const int b = bh >> 4, h = bh & 15;
  const int qb = (j & 15) * 128 + w * 32;  // wave's 32-q base
  const f16* Qp = Q + (size_t)bh * (2048 * 64);
  const f16* Kp = K + (size_t)bh * (2048 * 64);
  const f16* Vp = Vt + (size_t)bh * (64 * 2048);

  // Q as B-operand: col=q=cl (per half), k=d (pre-scaled by log2e/8)
  f16x8 bq[2][2];
#pragma unroll
  for (int qh = 0; qh < 2; ++qh) {
    bq[qh][0] = *(const f16x8*)(Qp + (qb + qh * 16 + cl) * 64 + g * 8);
    bq[qh][1] = *(const f16x8*)(Qp + (qb + qh * 16 + cl) * 64 + 32 + g * 8);
  }

  f32x4 acc[2][4] = {};   // acc[qh][dblk]: O^T[d=dblk*16+g*4+r][q]
  f32x4 acc1[2] = {};     // ones-MFMA denominator: acc1[qh][r] = sum_k P
  const f16x8 kones = {(f16)1, (f16)1, (f16)1, (f16)1,
                       (f16)1, (f16)1, (f16)1, (f16)1};
  const int vx = cl & 7;
  const f32x4 z4 = {0.f, 0.f, 0.f, 0.f};
  union PB { f16x8 v; f16x2 hx[4]; };
  struct AS { f32x4 s[2][4]; f16x8 vf[2][4]; };  // 64 VGPR per set

  // stage one 128-key tile (two 64-key halves): 8 gload_lds per wave
  auto STAGE = [&](int it, int bf) {
    const f16* kp = Kp + (size_t)it * 8192;
    const f16* vp = Vp + (size_t)it * 128;
#pragma unroll
    for (int hh = 0; hh < 2; ++hh) {
      stage_tile(kp + hh * 4096, 64, Ks[bf][hh], tid);
      stage_tile(kp + hh * 4096, 64, Ks[bf][hh], tid + 256);
      stage_tile(vp + hh * 64, 2048, Vs[bf][hh], tid);
      stage_tile(vp + hh * 64, 2048, Vs[bf][hh], tid + 256);
    }
  };

  // A-phase: K-frag reads + QK^T; V-frags pre-loaded to registers
  auto APH = [&](const f16* kb, const f16* vb, AS& S) {
    f16x8 a0[4], a1[4];
#pragma unroll
    for (int i = 0; i < 4; ++i) {
      const f16* kr = kb + (i * 16 + cl) * 64;
      a0[i] = *(const f16x8*)(kr + ((g ^ vx) << 3));
      a1[i] = *(const f16x8*)(kr + (((4 + g) ^ vx) << 3));
    }
#pragma unroll
    for (int ks = 0; ks < 2; ++ks)
#pragma unroll
      for (int d = 0; d < 4; ++d)
        S.vf[ks][d] = *(const f16x8*)(vb + (d * 16 + cl) * 64 +
                                      (((ks * 4 + g) ^ vx) << 3));
    __builtin_amdgcn_s_setprio(1);
#pragma unroll
    for (int qh = 0; qh < 2; ++qh)
#pragma unroll
      for (int i = 0; i < 4; ++i)
        S.s[qh][i] = mfma16(a1[i], bq[qh][1], mfma16(a0[i], bq[qh][0], z4));
    __builtin_amdgcn_s_setprio(0);
  };

  // B-phase: softmax (raw v_exp) + PV + ones-MFMA denominator
  auto BPH = [&](AS& S) {
    PB pb[2][2];
#pragma unroll
    for (int qh = 0; qh < 2; ++qh) {
      float p0 = fexp2(S.s[qh][0][0]), p1 = fexp2(S.s[qh][0][1]);
      float p2 = fexp2(S.s[qh][0][2]), p3 = fexp2(S.s[qh][0][3]);
      float p4 = fexp2(S.s[qh][1][0]), p5 = fexp2(S.s[qh][1][1]);
      float p6 = fexp2(S.s[qh][1][2]), p7 = fexp2(S.s[qh][1][3]);
      float p8 = fexp2(S.s[qh][2][0]), p9 = fexp2(S.s[qh][2][1]);
      float pa = fexp2(S.s[qh][2][2]), pc = fexp2(S.s[qh][2][3]);
      float pd = fexp2(S.s[qh][3][0]), pe = fexp2(S.s[qh][3][1]);
      float pf = fexp2(S.s[qh][3][2]), pg = fexp2(S.s[qh][3][3]);
      pb[qh][0].hx[0] = cvt2(p0, p1); pb[qh][0].hx[1] = cvt2(p2, p3);
      pb[qh][0].hx[2] = cvt2(p4, p5); pb[qh][0].hx[3] = cvt2(p6, p7);
      pb[qh][1].hx[0] = cvt2(p8, p9); pb[qh][1].hx[1] = cvt2(pa, pc);
      pb[qh][1].hx[2] = cvt2(pd, pe); pb[qh][1].hx[3] = cvt2(pf, pg);
    }
    __builtin_amdgcn_s_setprio(1);
#pragma unroll
    for (int ks = 0; ks < 2; ++ks) {
#pragma unroll
      for (int d = 0; d < 4; ++d) {
        acc[0][d] = mfma16(S.vf[ks][d], pb[0][ks].v, acc[0][d]);
        acc[1][d] = mfma16(S.vf[ks][d], pb[1][ks].v, acc[1][d]);
      }
      acc1[0] = mfma16(kones, pb[0][ks].v, acc1[0]);
      acc1[1] = mfma16(kones, pb[1][ks].v, acc1[1]);
    }
    __builtin_amdgcn_s_setprio(0);
  };

  // prologue
  STAGE(0, 0);
  asm volatile("s_waitcnt vmcnt(0)" ::: "memory");
  __builtin_amdgcn_s_barrier();
  STAGE(1, 1);
  AS P, Qs;
  APH(Ks[0][0], Vs[0][0], P);   // sub-tile 0

  for (int it = 0; it < 16; ++it) {
    const int c = it & 1;
    // sub-tile 2it+1 (same buffer) while finishing 2it
    APH(Ks[c][1], Vs[c][1], Qs);
    BPH(P);
    if (it < 15) {
      asm volatile("s_waitcnt vmcnt(0)" ::: "memory");  // tile it+1 landed
      __builtin_amdgcn_s_barrier();                      // buf c readers done
      if (it + 2 < 16) STAGE(it + 2, c);
      // sub-tile 2it+2 (next buffer) while finishing 2it+1
      APH(Ks[c ^ 1][0], Vs[c ^ 1][0], P);
      BPH(Qs);
    } else {
      BPH(Qs);
    }
  }

  // acc1[qh] already holds the FULL denominator per col q (MFMA summed
  // across all k-groups) — no cross-lane reduce needed.
#pragma unroll
  for (int qh = 0; qh < 2; ++qh) {
    float inv = 1.0f / acc1[qh][0];
    float* ob = out + (size_t)(b * 2048 + qb + qh * 16 + cl) * 1024 +
                h * 64 + g * 4;
#pragma unroll
    for (int d = 0; d < 4; ++d) {
      float4 o = {acc[qh][d][0] * inv, acc[qh][d][1] * inv,
                  acc[qh][d][2] * inv, acc[qh][d][3] * inv};
      *(float4*)(ob + (size_t)d * 16) = o;
    }
  }
}

extern "C" void kernel_launch(void* const* d_in, const int* in_sizes, int n_in,
                              void* d_out, int out_size, void* d_ws, size_t ws_size,
                              hipStream_t stream) {
  const float* x  = (const float*)d_in[0];
  const float* Wq = (const float*)d_in[1];
  const float* Wk = (const float*)d_in[2];
  const float* Wv = (const float*)d_in[3];
  float* out = (float*)d_out;
  char* ws = (char*)d_ws;

  f16* xh   = (f16*)(ws);                       // 8388608 B
  f16* wh   = (f16*)(ws + 8388608);             // 6291456 B
  f16* Qr   = (f16*)(ws + 14680064);            // 8388608 B
  f16* Kr   = (f16*)(ws + 23068672);            // 8388608 B
  f16* Vt   = (f16*)(ws + 31457280);            // 8388608 B
  float* cosT = (float*)(ws + 39845888);        // 262144 B
  float* sinT = (float*)(ws + 40108032);        // total ~40.4 MB

  convall<<<3840, 256, 0, stream>>>(x, Wq, Wk, Wv, xh, wh, cosT, sinT);

  qkv_gemm<<<768, 256, 0, stream>>>(xh, wh, cosT, sinT, Qr, Kr, Vt);

  attn<<<512, 256, 0, stream>>>(Qr, Kr, Vt, out);
}